// Round 1
// baseline (293.617 us; speedup 1.0000x reference)
//
#include <hip/hip_runtime.h>
#include <hip/hip_bf16.h>
#include <stdint.h>
#include <stddef.h>

#define AS1 __attribute__((address_space(1)))
#define AS3 __attribute__((address_space(3)))

typedef __attribute__((ext_vector_type(8))) __bf16 bf16x8;
typedef __attribute__((ext_vector_type(4))) float f32x4;
typedef __attribute__((ext_vector_type(4))) unsigned int u32x4;

static __device__ __forceinline__ unsigned short f2bf(float f) {
    unsigned u = __builtin_bit_cast(unsigned, f);
    u += 0x7FFFu + ((u >> 16) & 1u);
    return (unsigned short)(u >> 16);
}

// ---------------- kernel 1: t2 = depthwise (3,1) conv, store NHWC bf16, H padded by 9 ----
// t2p[n][hp][w][c], hp in [0,74): value = t2[n][c][hp-9][w], zero outside.
__global__ void k_t2prep(const float* __restrict__ x, const float* __restrict__ w2,
                         unsigned short* __restrict__ t2p) {
    const int b = blockIdx.x;
    const int n = b / 74, hp = b % 74;
    const int t = threadIdx.x;
    unsigned short* orow = t2p + (size_t)(n * 74 + hp) * (56 * 256);
    const int h = hp - 9;
    if (h < 0 || h >= 56) {
        u32x4 z = {0u, 0u, 0u, 0u};
        #pragma unroll
        for (int i = 0; i < 7; ++i)
            *(u32x4*)(orow + (size_t)(i * 256 + t) * 8) = z;
        return;
    }
    __shared__ float xs[3][64][57];
    __shared__ float w2s[64][3];
    for (int cc = 0; cc < 256; cc += 64) {
        if (cc) __syncthreads();
        if (t < 192) w2s[t / 3][t % 3] = w2[(cc + t / 3) * 3 + (t % 3)];
        for (int idx = t; idx < 2688; idx += 256) {
            int r = idx / 896, rem = idx % 896;
            int ci = rem / 14, q = rem % 14;
            int hy = h - 1 + r;
            f32x4 v = {0.f, 0.f, 0.f, 0.f};
            if (hy >= 0 && hy < 56)
                v = *(const f32x4*)(x + (size_t)((n * 256 + cc + ci) * 56 + hy) * 56 + q * 4);
            xs[r][ci][q * 4 + 0] = v[0];
            xs[r][ci][q * 4 + 1] = v[1];
            xs[r][ci][q * 4 + 2] = v[2];
            xs[r][ci][q * 4 + 3] = v[3];
        }
        __syncthreads();
        const int c = t & 63;
        const float a0 = w2s[c][0], a1 = w2s[c][1], a2 = w2s[c][2];
        #pragma unroll
        for (int i = 0; i < 14; ++i) {
            int w = i * 4 + (t >> 6);
            float v = a0 * xs[0][c][w] + a1 * xs[1][c][w] + a2 * xs[2][c][w];
            orow[w * 256 + cc + c] = f2bf(v);
        }
    }
}

// ---------------- kernel 1b: w4 reorder + bf16 convert: w4b[o][k*256+c] = w4[o][c*7+k] ----
__global__ void k_w4conv(const float* __restrict__ w4, unsigned short* __restrict__ w4b) {
    int tid = blockIdx.x * 256 + threadIdx.x;   // 458752 total, grid exact
    int o = tid / 1792, j = tid % 1792;
    int k = j >> 8, c = j & 255;
    w4b[tid] = f2bf(w4[o * 1792 + c * 7 + k]);
}

// ---------------- kernel 2: the GEMM (implicit unfold). out = t4 (fp32) ----------------
// A = w4b [256 x 1792] (i' = k*256+c), B[i'][pix] = t2p[n][h(pix)+3k][w(pix)][c]
// tile: 128 o x 128 pix, BK=64 (one k segment), 4 waves 2x2, 16x16x32 bf16 MFMA.
__global__ __launch_bounds__(256) void k_gemm(const unsigned short* __restrict__ w4b,
                                              const unsigned short* __restrict__ t2p,
                                              float* __restrict__ out) {
    const int pix0 = blockIdx.x * 128;
    const int o0   = blockIdx.y * 128;
    const int n    = blockIdx.z;
    const int t = threadIdx.x;
    const int l = t & 63, wv = t >> 6, wr = wv >> 1, wc = wv & 1;
    __shared__ __align__(16) unsigned short lds[16384];   // A: [0,16K) B: [16K,32K) bytes

    // staging: linear LDS dest, pre-swizzled global source (XOR slot ^ row&7, rule 21)
    const int st = (t & 7) ^ ((t >> 3) & 7);
    size_t aoff[4], boff[4];
    #pragma unroll
    for (int r = 0; r < 4; ++r) {
        int row = r * 32 + (t >> 3);
        aoff[r] = (size_t)(o0 + row) * 1792 + st * 8;
        int P = pix0 + row; if (P > 3135) P = 3135;   // clamp tail tile (unstored columns)
        int hh = P / 56, ww = P % 56;
        boff[r] = ((size_t)(n * 74 + hh) * 56 + ww) * 256 + st * 8;
    }

    f32x4 acc[4][4];
    #pragma unroll
    for (int m = 0; m < 4; ++m)
        #pragma unroll
        for (int nn = 0; nn < 4; ++nn)
            acc[m][nn] = (f32x4){0.f, 0.f, 0.f, 0.f};

    for (int k = 0; k < 7; ++k) {
        const size_t koff = (size_t)k * 3 * 56 * 256;   // h -> h+3k in t2p
        for (int cs = 0; cs < 4; ++cs) {
            const int i0 = k * 256 + cs * 64;
            __syncthreads();
            #pragma unroll
            for (int r = 0; r < 4; ++r)
                __builtin_amdgcn_global_load_lds(
                    (const AS1 void*)(w4b + aoff[r] + i0),
                    (AS3 void*)((char*)lds + r * 4096 + wv * 1024), 16, 0, 0);
            #pragma unroll
            for (int r = 0; r < 4; ++r)
                __builtin_amdgcn_global_load_lds(
                    (const AS1 void*)(t2p + boff[r] + koff + cs * 64),
                    (AS3 void*)((char*)lds + 16384 + r * 4096 + wv * 1024), 16, 0, 0);
            __syncthreads();

            bf16x8 af[4][2], bfr[4][2];
            const int lr = l & 15, lg = l >> 4;
            #pragma unroll
            for (int m = 0; m < 4; ++m) {
                int row = wr * 64 + m * 16 + lr;
                const char* base = (const char*)lds + row * 128;
                af[m][0] = *(const bf16x8*)(base + (((lg) ^ (row & 7)) << 4));
                af[m][1] = *(const bf16x8*)(base + (((4 + lg) ^ (row & 7)) << 4));
            }
            #pragma unroll
            for (int nn = 0; nn < 4; ++nn) {
                int row = wc * 64 + nn * 16 + lr;
                const char* base = (const char*)lds + 16384 + row * 128;
                bfr[nn][0] = *(const bf16x8*)(base + (((lg) ^ (row & 7)) << 4));
                bfr[nn][1] = *(const bf16x8*)(base + (((4 + lg) ^ (row & 7)) << 4));
            }
            #pragma unroll
            for (int m = 0; m < 4; ++m)
                #pragma unroll
                for (int nn = 0; nn < 4; ++nn) {
                    acc[m][nn] = __builtin_amdgcn_mfma_f32_16x16x32_bf16(af[m][0], bfr[nn][0], acc[m][nn], 0, 0, 0);
                    acc[m][nn] = __builtin_amdgcn_mfma_f32_16x16x32_bf16(af[m][1], bfr[nn][1], acc[m][nn], 0, 0, 0);
                }
        }
    }

    // epilogue: C/D layout col=lane&15, row=(lane>>4)*4+j  [HW-verified]
    #pragma unroll
    for (int m = 0; m < 4; ++m) {
        int o = o0 + wr * 64 + m * 16 + (l >> 4) * 4;
        #pragma unroll
        for (int nn = 0; nn < 4; ++nn) {
            int P = pix0 + wc * 64 + nn * 16 + (l & 15);
            if (P < 3136) {
                float* op = out + (size_t)(n * 256 + o) * 3136 + P;
                op[0 * 3136] = acc[m][nn][0];
                op[1 * 3136] = acc[m][nn][1];
                op[2 * 3136] = acc[m][nn][2];
                op[3 * 3136] = acc[m][nn][3];
            }
        }
    }
}

// ---------------- kernel 3: out *= t1 (depthwise 5x5 computed on the fly) ----------------
__global__ void k_gate(const float* __restrict__ x, const float* __restrict__ w1,
                       float* __restrict__ out) {
    int b = blockIdx.x;
    int hq = b % 14;
    int c = (b / 14) & 255;
    int n = b / (14 * 256);
    int t = threadIdx.x;
    int w = t & 63, dh = t >> 6;
    if (w >= 56) return;
    int h = hq * 4 + dh;
    const float* xc = x + (size_t)(n * 256 + c) * 3136;
    const float* wk = w1 + c * 25;
    float t1 = 0.f;
    #pragma unroll
    for (int dy = 0; dy < 5; ++dy) {
        int hy = h + dy - 2;
        if (hy < 0 || hy >= 56) continue;
        #pragma unroll
        for (int dx = 0; dx < 5; ++dx) {
            int wx = w + dx - 2;
            if (wx < 0 || wx >= 56) continue;
            t1 = fmaf(wk[dy * 5 + dx], xc[hy * 56 + wx], t1);
        }
    }
    size_t idx = (size_t)(n * 256 + c) * 3136 + (size_t)h * 56 + w;
    out[idx] *= t1;
}

extern "C" void kernel_launch(void* const* d_in, const int* in_sizes, int n_in,
                              void* d_out, int out_size, void* d_ws, size_t ws_size,
                              hipStream_t stream) {
    const float* x  = (const float*)d_in[0];
    const float* w1 = (const float*)d_in[1];
    const float* w2 = (const float*)d_in[2];
    const float* w4 = (const float*)d_in[3];
    float* out = (float*)d_out;

    // workspace layout: w4b bf16 [256*1792], then t2p bf16 [16][74][56][256]
    const size_t W4B_ELEMS = 256 * 1792;              // 458752
    const size_t T2P_ELEMS = (size_t)16 * 74 * 56 * 256;
    if (ws_size < (W4B_ELEMS + T2P_ELEMS) * sizeof(unsigned short)) return; // safety
    unsigned short* w4b = (unsigned short*)d_ws;
    unsigned short* t2p = w4b + W4B_ELEMS;

    k_w4conv<<<1792, 256, 0, stream>>>(w4, w4b);
    k_t2prep<<<16 * 74, 256, 0, stream>>>(x, w2, t2p);
    k_gemm<<<dim3(25, 2, 16), 256, 0, stream>>>(w4b, t2p, out);
    k_gate<<<57344, 256, 0, stream>>>(x, w1, out);
}

// Round 2
// 154.267 us; speedup vs baseline: 1.9033x; 1.9033x over previous
//
#include <hip/hip_runtime.h>
#include <hip/hip_bf16.h>
#include <stdint.h>
#include <stddef.h>

#define AS1 __attribute__((address_space(1)))
#define AS3 __attribute__((address_space(3)))

typedef __attribute__((ext_vector_type(8))) __bf16 bf16x8;
typedef __attribute__((ext_vector_type(4))) float f32x4;
typedef __attribute__((ext_vector_type(4))) unsigned int u32x4;

static __device__ __forceinline__ unsigned short f2bf(float f) {
    unsigned u = __builtin_bit_cast(unsigned, f);
    u += 0x7FFFu + ((u >> 16) & 1u);
    return (unsigned short)(u >> 16);
}

// ---------------- kernel 1: t2 = depthwise (3,1) conv, store NHWC bf16, H padded by 9 ----
// t2p[n][hp][w][c], hp in [0,74): value = t2[n][c][hp-9][w], zero outside.
__global__ void k_t2prep(const float* __restrict__ x, const float* __restrict__ w2,
                         unsigned short* __restrict__ t2p) {
    const int b = blockIdx.x;
    const int n = b / 74, hp = b % 74;
    const int t = threadIdx.x;
    unsigned short* orow = t2p + (size_t)(n * 74 + hp) * (56 * 256);
    const int h = hp - 9;
    if (h < 0 || h >= 56) {
        u32x4 z = {0u, 0u, 0u, 0u};
        #pragma unroll
        for (int i = 0; i < 7; ++i)
            *(u32x4*)(orow + (size_t)(i * 256 + t) * 8) = z;
        return;
    }
    __shared__ float xs[3][64][57];
    __shared__ float w2s[64][3];
    for (int cc = 0; cc < 256; cc += 64) {
        if (cc) __syncthreads();
        if (t < 192) w2s[t / 3][t % 3] = w2[(cc + t / 3) * 3 + (t % 3)];
        for (int idx = t; idx < 2688; idx += 256) {
            int r = idx / 896, rem = idx % 896;
            int ci = rem / 14, q = rem % 14;
            int hy = h - 1 + r;
            f32x4 v = {0.f, 0.f, 0.f, 0.f};
            if (hy >= 0 && hy < 56)
                v = *(const f32x4*)(x + (size_t)((n * 256 + cc + ci) * 56 + hy) * 56 + q * 4);
            xs[r][ci][q * 4 + 0] = v[0];
            xs[r][ci][q * 4 + 1] = v[1];
            xs[r][ci][q * 4 + 2] = v[2];
            xs[r][ci][q * 4 + 3] = v[3];
        }
        __syncthreads();
        const int c = t & 63;
        const float a0 = w2s[c][0], a1 = w2s[c][1], a2 = w2s[c][2];
        #pragma unroll
        for (int i = 0; i < 14; ++i) {
            int w = i * 4 + (t >> 6);
            float v = a0 * xs[0][c][w] + a1 * xs[1][c][w] + a2 * xs[2][c][w];
            orow[w * 256 + cc + c] = f2bf(v);
        }
    }
}

// ---------------- kernel 1b: w4 reorder + bf16 convert: w4b[o][k*256+c] = w4[o][c*7+k] ----
__global__ void k_w4conv(const float* __restrict__ w4, unsigned short* __restrict__ w4b) {
    int tid = blockIdx.x * 256 + threadIdx.x;   // 458752 total, grid exact
    int o = tid / 1792, j = tid % 1792;
    int k = j >> 8, c = j & 255;
    w4b[tid] = f2bf(w4[o * 1792 + c * 7 + k]);
}

// ---------------- kernel 2: the GEMM (implicit unfold). out = t4 (fp32) ----------------
// A = w4b [256 x 1792] (i' = k*256+c), B[i'][pix] = t2p[n][h(pix)+3k][w(pix)][c]
// tile: 128 o x 128 pix, BK=64 (one k segment), 4 waves 2x2, 16x16x32 bf16 MFMA.
__global__ __launch_bounds__(256) void k_gemm(const unsigned short* __restrict__ w4b,
                                              const unsigned short* __restrict__ t2p,
                                              float* __restrict__ out) {
    const int pix0 = blockIdx.x * 128;
    const int o0   = blockIdx.y * 128;
    const int n    = blockIdx.z;
    const int t = threadIdx.x;
    const int l = t & 63, wv = t >> 6, wr = wv >> 1, wc = wv & 1;
    __shared__ __align__(16) unsigned short lds[16384];   // A: [0,16K) B: [16K,32K) bytes

    // staging: linear LDS dest, pre-swizzled global source (XOR slot ^ row&7, rule 21)
    const int st = (t & 7) ^ ((t >> 3) & 7);
    size_t aoff[4], boff[4];
    #pragma unroll
    for (int r = 0; r < 4; ++r) {
        int row = r * 32 + (t >> 3);
        aoff[r] = (size_t)(o0 + row) * 1792 + st * 8;
        int P = pix0 + row; if (P > 3135) P = 3135;   // clamp tail tile (unstored columns)
        int hh = P / 56, ww = P % 56;
        boff[r] = ((size_t)(n * 74 + hh) * 56 + ww) * 256 + st * 8;
    }

    f32x4 acc[4][4];
    #pragma unroll
    for (int m = 0; m < 4; ++m)
        #pragma unroll
        for (int nn = 0; nn < 4; ++nn)
            acc[m][nn] = (f32x4){0.f, 0.f, 0.f, 0.f};

    for (int k = 0; k < 7; ++k) {
        const size_t koff = (size_t)k * 3 * 56 * 256;   // h -> h+3k in t2p
        for (int cs = 0; cs < 4; ++cs) {
            const int i0 = k * 256 + cs * 64;
            __syncthreads();
            #pragma unroll
            for (int r = 0; r < 4; ++r)
                __builtin_amdgcn_global_load_lds(
                    (const AS1 void*)(w4b + aoff[r] + i0),
                    (AS3 void*)((char*)lds + r * 4096 + wv * 1024), 16, 0, 0);
            #pragma unroll
            for (int r = 0; r < 4; ++r)
                __builtin_amdgcn_global_load_lds(
                    (const AS1 void*)(t2p + boff[r] + koff + cs * 64),
                    (AS3 void*)((char*)lds + 16384 + r * 4096 + wv * 1024), 16, 0, 0);
            __syncthreads();

            bf16x8 af[4][2], bfr[4][2];
            const int lr = l & 15, lg = l >> 4;
            #pragma unroll
            for (int m = 0; m < 4; ++m) {
                int row = wr * 64 + m * 16 + lr;
                const char* base = (const char*)lds + row * 128;
                af[m][0] = *(const bf16x8*)(base + (((lg) ^ (row & 7)) << 4));
                af[m][1] = *(const bf16x8*)(base + (((4 + lg) ^ (row & 7)) << 4));
            }
            #pragma unroll
            for (int nn = 0; nn < 4; ++nn) {
                int row = wc * 64 + nn * 16 + lr;
                const char* base = (const char*)lds + 16384 + row * 128;
                bfr[nn][0] = *(const bf16x8*)(base + (((lg) ^ (row & 7)) << 4));
                bfr[nn][1] = *(const bf16x8*)(base + (((4 + lg) ^ (row & 7)) << 4));
            }
            #pragma unroll
            for (int m = 0; m < 4; ++m)
                #pragma unroll
                for (int nn = 0; nn < 4; ++nn) {
                    acc[m][nn] = __builtin_amdgcn_mfma_f32_16x16x32_bf16(af[m][0], bfr[nn][0], acc[m][nn], 0, 0, 0);
                    acc[m][nn] = __builtin_amdgcn_mfma_f32_16x16x32_bf16(af[m][1], bfr[nn][1], acc[m][nn], 0, 0, 0);
                }
        }
    }

    // epilogue: C/D layout col=lane&15, row=(lane>>4)*4+j  [HW-verified]
    #pragma unroll
    for (int m = 0; m < 4; ++m) {
        int o = o0 + wr * 64 + m * 16 + (l >> 4) * 4;
        #pragma unroll
        for (int nn = 0; nn < 4; ++nn) {
            int P = pix0 + wc * 64 + nn * 16 + (l & 15);
            if (P < 3136) {
                float* op = out + (size_t)(n * 256 + o) * 3136 + P;
                op[0 * 3136] = acc[m][nn][0];
                op[1 * 3136] = acc[m][nn][1];
                op[2 * 3136] = acc[m][nn][2];
                op[3 * 3136] = acc[m][nn][3];
            }
        }
    }
}

// ---------------- kernel 3: out *= t1 (depthwise 5x5, LDS-tiled per (n,c) plane) --------
__global__ __launch_bounds__(256) void k_gate(const float* __restrict__ x,
                                              const float* __restrict__ w1,
                                              float* __restrict__ out) {
    const int b = blockIdx.x;
    const int c = b & 255, n = b >> 8;
    const int t = threadIdx.x;
    __shared__ float xs[60][60];   // zero-padded halo of 2 on each side

    // zero the whole tile (borders matter), then load interior
    float* lp = &xs[0][0];
    #pragma unroll
    for (int i = 0; i < 15; ++i) {
        int idx = t + i * 256;
        if (idx < 3600) lp[idx] = 0.f;
    }
    __syncthreads();

    const float* xc = x + (size_t)(n * 256 + c) * 3136;
    #pragma unroll
    for (int k = 0; k < 4; ++k) {
        int j = t + k * 256;          // 784 float4 = whole plane
        if (j < 784) {
            f32x4 v = *(const f32x4*)(xc + j * 4);
            int p = j * 4;
            int h = p / 56, w = p % 56;
            xs[h + 2][w + 2 + 0] = v[0];
            xs[h + 2][w + 2 + 1] = v[1];
            xs[h + 2][w + 2 + 2] = v[2];
            xs[h + 2][w + 2 + 3] = v[3];
        }
    }

    // weights: wave-uniform (same c for whole block) -> scalar loads
    const float* wk = w1 + c * 25;
    float wr[25];
    #pragma unroll
    for (int i = 0; i < 25; ++i) wr[i] = wk[i];
    __syncthreads();

    float* oc = out + (size_t)(n * 256 + c) * 3136;
    #pragma unroll
    for (int k = 0; k < 4; ++k) {
        int j = t + k * 256;
        if (j < 784) {
            int p = j * 4;
            int h = p / 56, w = p % 56;
            f32x4 o = *(f32x4*)(oc + p);
            f32x4 t1 = {0.f, 0.f, 0.f, 0.f};
            #pragma unroll
            for (int dy = 0; dy < 5; ++dy)
                #pragma unroll
                for (int dx = 0; dx < 5; ++dx) {
                    float wv = wr[dy * 5 + dx];
                    t1[0] = fmaf(wv, xs[h + dy][w + dx + 0], t1[0]);
                    t1[1] = fmaf(wv, xs[h + dy][w + dx + 1], t1[1]);
                    t1[2] = fmaf(wv, xs[h + dy][w + dx + 2], t1[2]);
                    t1[3] = fmaf(wv, xs[h + dy][w + dx + 3], t1[3]);
                }
            o *= t1;
            *(f32x4*)(oc + p) = o;
        }
    }
}

extern "C" void kernel_launch(void* const* d_in, const int* in_sizes, int n_in,
                              void* d_out, int out_size, void* d_ws, size_t ws_size,
                              hipStream_t stream) {
    const float* x  = (const float*)d_in[0];
    const float* w1 = (const float*)d_in[1];
    const float* w2 = (const float*)d_in[2];
    const float* w4 = (const float*)d_in[3];
    float* out = (float*)d_out;

    // workspace layout: w4b bf16 [256*1792], then t2p bf16 [16][74][56][256]
    const size_t W4B_ELEMS = 256 * 1792;              // 458752
    const size_t T2P_ELEMS = (size_t)16 * 74 * 56 * 256;
    if (ws_size < (W4B_ELEMS + T2P_ELEMS) * sizeof(unsigned short)) return; // safety
    unsigned short* w4b = (unsigned short*)d_ws;
    unsigned short* t2p = w4b + W4B_ELEMS;

    k_w4conv<<<1792, 256, 0, stream>>>(w4, w4b);
    k_t2prep<<<16 * 74, 256, 0, stream>>>(x, w2, t2p);
    k_gemm<<<dim3(25, 2, 16), 256, 0, stream>>>(w4b, t2p, out);
    k_gate<<<4096, 256, 0, stream>>>(x, w1, out);
}

// Round 3
// 148.223 us; speedup vs baseline: 1.9809x; 1.0408x over previous
//
#include <hip/hip_runtime.h>
#include <hip/hip_bf16.h>
#include <stdint.h>
#include <stddef.h>

#define AS1 __attribute__((address_space(1)))
#define AS3 __attribute__((address_space(3)))

typedef __attribute__((ext_vector_type(8))) __bf16 bf16x8;
typedef __attribute__((ext_vector_type(4))) float f32x4;
typedef __attribute__((ext_vector_type(4))) unsigned int u32x4;

static __device__ __forceinline__ unsigned short f2bf(float f) {
    unsigned u = __builtin_bit_cast(unsigned, f);
    u += 0x7FFFu + ((u >> 16) & 1u);
    return (unsigned short)(u >> 16);
}

// ---------------- kernel 1: t2 = depthwise (3,1) conv, store NHWC bf16, H padded by 9 ----
__global__ void k_t2prep(const float* __restrict__ x, const float* __restrict__ w2,
                         unsigned short* __restrict__ t2p) {
    const int b = blockIdx.x;
    const int n = b / 74, hp = b % 74;
    const int t = threadIdx.x;
    unsigned short* orow = t2p + (size_t)(n * 74 + hp) * (56 * 256);
    const int h = hp - 9;
    if (h < 0 || h >= 56) {
        u32x4 z = {0u, 0u, 0u, 0u};
        #pragma unroll
        for (int i = 0; i < 7; ++i)
            *(u32x4*)(orow + (size_t)(i * 256 + t) * 8) = z;
        return;
    }
    __shared__ float xs[3][64][57];
    __shared__ float w2s[64][3];
    for (int cc = 0; cc < 256; cc += 64) {
        if (cc) __syncthreads();
        if (t < 192) w2s[t / 3][t % 3] = w2[(cc + t / 3) * 3 + (t % 3)];
        for (int idx = t; idx < 2688; idx += 256) {
            int r = idx / 896, rem = idx % 896;
            int ci = rem / 14, q = rem % 14;
            int hy = h - 1 + r;
            f32x4 v = {0.f, 0.f, 0.f, 0.f};
            if (hy >= 0 && hy < 56)
                v = *(const f32x4*)(x + (size_t)((n * 256 + cc + ci) * 56 + hy) * 56 + q * 4);
            xs[r][ci][q * 4 + 0] = v[0];
            xs[r][ci][q * 4 + 1] = v[1];
            xs[r][ci][q * 4 + 2] = v[2];
            xs[r][ci][q * 4 + 3] = v[3];
        }
        __syncthreads();
        const int c = t & 63;
        const float a0 = w2s[c][0], a1 = w2s[c][1], a2 = w2s[c][2];
        #pragma unroll
        for (int i = 0; i < 14; ++i) {
            int w = i * 4 + (t >> 6);
            float v = a0 * xs[0][c][w] + a1 * xs[1][c][w] + a2 * xs[2][c][w];
            orow[w * 256 + cc + c] = f2bf(v);
        }
    }
}

// ---------------- kernel 1b: w4 reorder + bf16 convert: w4b[o][k*256+c] = w4[o][c*7+k] ----
__global__ void k_w4conv(const float* __restrict__ w4, unsigned short* __restrict__ w4b) {
    int tid = blockIdx.x * 256 + threadIdx.x;
    int o = tid / 1792, j = tid % 1792;
    int k = j >> 8, c = j & 255;
    w4b[tid] = f2bf(w4[o * 1792 + c * 7 + k]);
}

// ---------------- kernel 2: 8-phase 256x256 GEMM (implicit unfold), counted vmcnt -------
// A = w4b [256 o x 1792 K], B[K][pix] from t2p NHWC. BK=64, 28 K-tiles, dbuf LDS 128KB.
// 8 waves: wr = pixel half (2), wc = o quarter (4); per-wave C = 128 pix x 64 o.
__global__ __launch_bounds__(512, 2) void k_gemm8(const unsigned short* __restrict__ w4b,
                                                  const unsigned short* __restrict__ t2p,
                                                  float* __restrict__ out) {
    extern __shared__ char lds[];                 // 131072 B: [buf][A 32K | B 32K]
    const int pix0 = blockIdx.x * 256;
    const int t = threadIdx.x;
    const int l = t & 63, wv = t >> 6;
    const int wr = wv >> 2, wc = wv & 3;

    // ---- staging bases (bytes), pre-swizzled source (rule 21 involution) ----
    const int srow = t >> 3;                      // 0..63 within a 64-row load
    const int segp = (t & 7) ^ (srow & 7);
    unsigned abase[4], bbase[4];
    #pragma unroll
    for (int j = 0; j < 4; ++j) {
        int arow = j * 64 + srow;                 // o row
        abase[j] = (unsigned)arow * 3584u + (unsigned)segp * 16u;
        int P = pix0 + j * 64 + srow;             // pixel row (always < 50176)
        int n = P / 3136, r = P % 3136;
        int hh = r / 56, ww = r % 56;
        bbase[j] = (unsigned)(((n * 74 + hh) * 56 + ww) * 512) + (unsigned)segp * 16u;
    }
    const char* w4c = (const char*)w4b;
    const char* t2c = (const char*)t2p;

#define STAGE(kk_, boff_) do {                                                        \
    unsigned _ao = (unsigned)(kk_) * 128u;                                            \
    unsigned _bo = (unsigned)((kk_) >> 2) * 86016u + (unsigned)((kk_) & 3) * 128u;    \
    _Pragma("unroll")                                                                 \
    for (int _j = 0; _j < 4; ++_j)                                                    \
        __builtin_amdgcn_global_load_lds((const AS1 void*)(w4c + abase[_j] + _ao),    \
            (AS3 void*)(lds + (boff_) + _j * 8192 + wv * 1024), 16, 0, 0);            \
    _Pragma("unroll")                                                                 \
    for (int _j = 0; _j < 4; ++_j)                                                    \
        __builtin_amdgcn_global_load_lds((const AS1 void*)(t2c + bbase[_j] + _bo),    \
            (AS3 void*)(lds + (boff_) + 32768 + _j * 8192 + wv * 1024), 16, 0, 0);    \
} while (0)

    // ---- fragment-read constants ----
    const int lr = l & 15, lg = l >> 4;
    const int sx = lr & 7;
    const unsigned fo0 = (unsigned)((lg ^ sx) << 4);
    const unsigned fo1 = (unsigned)(((lg + 4) ^ sx) << 4);
    const unsigned aRow = (unsigned)(wc * 8192 + lr * 128);            // + nn*2048
    const unsigned bRow = (unsigned)(32768 + wr * 16384 + lr * 128);   // + m*2048

    f32x4 acc[8][4];
    #pragma unroll
    for (int m = 0; m < 8; ++m)
        #pragma unroll
        for (int nn = 0; nn < 4; ++nn)
            acc[m][nn] = (f32x4){0.f, 0.f, 0.f, 0.f};

    bf16x8 afrag[4][2], bfrag[4][2];

    STAGE(0, 0);   // prologue: K-tile 0 -> buf0

    for (int kk = 0; kk < 28; ++kk) {
        const unsigned cur = (unsigned)(kk & 1) * 65536u;
        const unsigned nxt = cur ^ 65536u;
        const int kst = (kk < 27) ? kk + 1 : 27;  // last tile: redundant self-stage keeps vmcnt uniform

        // ========== phase 1: quadrant (pix half 0, o half 0) ==========
        STAGE(kst, nxt);
        asm volatile("s_waitcnt vmcnt(8)" ::: "memory");  // exactly tile-kk's 8 loads drained
        __builtin_amdgcn_s_barrier();                     // cross-wave: all stages landed
        asm volatile("" ::: "memory");
        #pragma unroll
        for (int m = 0; m < 4; ++m) {
            bfrag[m][0] = *(const bf16x8*)(lds + cur + bRow + m * 2048 + fo0);
            bfrag[m][1] = *(const bf16x8*)(lds + cur + bRow + m * 2048 + fo1);
        }
        #pragma unroll
        for (int nn = 0; nn < 2; ++nn) {
            afrag[nn][0] = *(const bf16x8*)(lds + cur + aRow + nn * 2048 + fo0);
            afrag[nn][1] = *(const bf16x8*)(lds + cur + aRow + nn * 2048 + fo1);
        }
        __builtin_amdgcn_s_setprio(1);
        #pragma unroll
        for (int m = 0; m < 4; ++m)
            #pragma unroll
            for (int nn = 0; nn < 2; ++nn) {
                acc[m][nn] = __builtin_amdgcn_mfma_f32_16x16x32_bf16(afrag[nn][0], bfrag[m][0], acc[m][nn], 0, 0, 0);
                acc[m][nn] = __builtin_amdgcn_mfma_f32_16x16x32_bf16(afrag[nn][1], bfrag[m][1], acc[m][nn], 0, 0, 0);
            }
        __builtin_amdgcn_s_setprio(0);
        __builtin_amdgcn_s_barrier();
        asm volatile("" ::: "memory");

        // ========== phase 2: (pix half 0, o half 1) — read a nn=2,3 ==========
        #pragma unroll
        for (int nn = 2; nn < 4; ++nn) {
            afrag[nn][0] = *(const bf16x8*)(lds + cur + aRow + nn * 2048 + fo0);
            afrag[nn][1] = *(const bf16x8*)(lds + cur + aRow + nn * 2048 + fo1);
        }
        __builtin_amdgcn_s_setprio(1);
        #pragma unroll
        for (int m = 0; m < 4; ++m)
            #pragma unroll
            for (int nn = 2; nn < 4; ++nn) {
                acc[m][nn] = __builtin_amdgcn_mfma_f32_16x16x32_bf16(afrag[nn][0], bfrag[m][0], acc[m][nn], 0, 0, 0);
                acc[m][nn] = __builtin_amdgcn_mfma_f32_16x16x32_bf16(afrag[nn][1], bfrag[m][1], acc[m][nn], 0, 0, 0);
            }
        __builtin_amdgcn_s_setprio(0);
        __builtin_amdgcn_s_barrier();
        asm volatile("" ::: "memory");

        // ========== phase 3: (pix half 1, o half 1) — read b m=4..7 ==========
        #pragma unroll
        for (int mb = 0; mb < 4; ++mb) {
            bfrag[mb][0] = *(const bf16x8*)(lds + cur + bRow + (4 + mb) * 2048 + fo0);
            bfrag[mb][1] = *(const bf16x8*)(lds + cur + bRow + (4 + mb) * 2048 + fo1);
        }
        __builtin_amdgcn_s_setprio(1);
        #pragma unroll
        for (int mb = 0; mb < 4; ++mb)
            #pragma unroll
            for (int nn = 2; nn < 4; ++nn) {
                acc[4 + mb][nn] = __builtin_amdgcn_mfma_f32_16x16x32_bf16(afrag[nn][0], bfrag[mb][0], acc[4 + mb][nn], 0, 0, 0);
                acc[4 + mb][nn] = __builtin_amdgcn_mfma_f32_16x16x32_bf16(afrag[nn][1], bfrag[mb][1], acc[4 + mb][nn], 0, 0, 0);
            }
        __builtin_amdgcn_s_setprio(0);
        __builtin_amdgcn_s_barrier();
        asm volatile("" ::: "memory");

        // ========== phase 4: (pix half 1, o half 0) — no new reads ==========
        __builtin_amdgcn_s_setprio(1);
        #pragma unroll
        for (int mb = 0; mb < 4; ++mb)
            #pragma unroll
            for (int nn = 0; nn < 2; ++nn) {
                acc[4 + mb][nn] = __builtin_amdgcn_mfma_f32_16x16x32_bf16(afrag[nn][0], bfrag[mb][0], acc[4 + mb][nn], 0, 0, 0);
                acc[4 + mb][nn] = __builtin_amdgcn_mfma_f32_16x16x32_bf16(afrag[nn][1], bfrag[mb][1], acc[4 + mb][nn], 0, 0, 0);
            }
        __builtin_amdgcn_s_setprio(0);
        __builtin_amdgcn_s_barrier();       // protects buf^1 before next p1 overwrites it
        asm volatile("" ::: "memory");
    }
#undef STAGE

    // ---- epilogue: C/D layout col(pix)=lane&15, row(o)=(lane>>4)*4+j ----
    #pragma unroll
    for (int m = 0; m < 8; ++m) {
        int P = pix0 + wr * 128 + m * 16 + lr;
        int n = P / 3136, p = P % 3136;
        float* obase = out + (size_t)n * 256 * 3136 + p;
        #pragma unroll
        for (int nn = 0; nn < 4; ++nn) {
            int o = wc * 64 + nn * 16 + lg * 4;
            float* op = obase + (size_t)o * 3136;
            op[0 * 3136] = acc[m][nn][0];
            op[1 * 3136] = acc[m][nn][1];
            op[2 * 3136] = acc[m][nn][2];
            op[3 * 3136] = acc[m][nn][3];
        }
    }
}

// ---------------- kernel 3: out *= t1 (depthwise 5x5, LDS-tiled per (n,c) plane) --------
__global__ __launch_bounds__(256) void k_gate(const float* __restrict__ x,
                                              const float* __restrict__ w1,
                                              float* __restrict__ out) {
    const int b = blockIdx.x;
    const int c = b & 255, n = b >> 8;
    const int t = threadIdx.x;
    __shared__ float xs[60][60];

    float* lp = &xs[0][0];
    #pragma unroll
    for (int i = 0; i < 15; ++i) {
        int idx = t + i * 256;
        if (idx < 3600) lp[idx] = 0.f;
    }
    __syncthreads();

    const float* xc = x + (size_t)(n * 256 + c) * 3136;
    #pragma unroll
    for (int k = 0; k < 4; ++k) {
        int j = t + k * 256;
        if (j < 784) {
            f32x4 v = *(const f32x4*)(xc + j * 4);
            int p = j * 4;
            int h = p / 56, w = p % 56;
            xs[h + 2][w + 2 + 0] = v[0];
            xs[h + 2][w + 2 + 1] = v[1];
            xs[h + 2][w + 2 + 2] = v[2];
            xs[h + 2][w + 2 + 3] = v[3];
        }
    }

    const float* wk = w1 + c * 25;
    float wr[25];
    #pragma unroll
    for (int i = 0; i < 25; ++i) wr[i] = wk[i];
    __syncthreads();

    float* oc = out + (size_t)(n * 256 + c) * 3136;
    #pragma unroll
    for (int k = 0; k < 4; ++k) {
        int j = t + k * 256;
        if (j < 784) {
            int p = j * 4;
            int h = p / 56, w = p % 56;
            f32x4 o = *(f32x4*)(oc + p);
            f32x4 t1 = {0.f, 0.f, 0.f, 0.f};
            #pragma unroll
            for (int dy = 0; dy < 5; ++dy)
                #pragma unroll
                for (int dx = 0; dx < 5; ++dx) {
                    float wv = wr[dy * 5 + dx];
                    t1[0] = fmaf(wv, xs[h + dy][w + dx + 0], t1[0]);
                    t1[1] = fmaf(wv, xs[h + dy][w + dx + 1], t1[1]);
                    t1[2] = fmaf(wv, xs[h + dy][w + dx + 2], t1[2]);
                    t1[3] = fmaf(wv, xs[h + dy][w + dx + 3], t1[3]);
                }
            o *= t1;
            *(f32x4*)(oc + p) = o;
        }
    }
}

extern "C" void kernel_launch(void* const* d_in, const int* in_sizes, int n_in,
                              void* d_out, int out_size, void* d_ws, size_t ws_size,
                              hipStream_t stream) {
    const float* x  = (const float*)d_in[0];
    const float* w1 = (const float*)d_in[1];
    const float* w2 = (const float*)d_in[2];
    const float* w4 = (const float*)d_in[3];
    float* out = (float*)d_out;

    const size_t W4B_ELEMS = 256 * 1792;
    const size_t T2P_ELEMS = (size_t)16 * 74 * 56 * 256;
    if (ws_size < (W4B_ELEMS + T2P_ELEMS) * sizeof(unsigned short)) return;
    unsigned short* w4b = (unsigned short*)d_ws;
    unsigned short* t2p = w4b + W4B_ELEMS;

    k_w4conv<<<1792, 256, 0, stream>>>(w4, w4b);
    k_t2prep<<<16 * 74, 256, 0, stream>>>(x, w2, t2p);
    k_gemm8<<<196, 512, 131072, stream>>>(w4b, t2p, out);
    k_gate<<<4096, 256, 0, stream>>>(x, w1, out);
}